// Round 23
// baseline (69.783 us; speedup 1.0000x reference)
//
#include <hip/hip_runtime.h>
#include <hip/hip_bf16.h>
#include <math.h>

#define N_NODES 50000
#define N_EDGES 800000
#define IN_F 256
#define OUT_F 64

#define BKT 256            // nodes per bucket
#define NB 196             // ceil(50000/256)
#define CAP 6144           // fixed per-bucket capacity (mean 4096, sigma 64)
#define PARTA_BLOCKS 400   // 800000/400 = 2000 edges/block
#define EPB (N_EDGES / PARTA_BLOCKS)   // 2000
#define GEMM_BM 32
#define GEMM_TILES 1563    // ceil(50000/32)
#define HIST_CHUNK 8192    // 7 chunks x 16 slices = 112 blocks, 32.8 KB LDS
#define HIST_BLOCKS 112

typedef __attribute__((ext_vector_type(8))) short bf16x8;
typedef __attribute__((ext_vector_type(4))) float f32x4;

__device__ __forceinline__ ushort f2bf(float x) {
    __hip_bfloat16 b = __float2bfloat16(x);   // RNE
    return *reinterpret_cast<ushort*>(&b);
}
__device__ __forceinline__ float bf_lo(uint v) { return __uint_as_float(v << 16); }
__device__ __forceinline__ float bf_hi(uint v) { return __uint_as_float(v & 0xffff0000u); }

// ---------------------------------------------------------------------------
// 0) prep: block 0 zeros bcntD; blocks 1..8 pack W into bf16 MFMA B-frag
//    layout; blocks 9+ zero outdeg (12500 int4).
// ---------------------------------------------------------------------------
__global__ __launch_bounds__(256) void prep_kernel(int* __restrict__ bcntD,
                                                   const float* __restrict__ W,
                                                   ushort* __restrict__ Wpk,
                                                   int4* __restrict__ outdeg4) {
    const int tid = threadIdx.x;
    if (blockIdx.x == 0) {
        for (int i = tid; i < NB; i += 256) bcntD[i] = 0;
    } else if (blockIdx.x < 9) {
        const int gid = (blockIdx.x - 1) * 256 + tid;   // 0..2047
        const int lane = gid & 63;
        const int ct = (gid >> 6) & 3;
        const int step = gid >> 8;
        const int kg = lane >> 4;
        const int n = lane & 15;
        const float* base = W + (size_t)(step * 32 + kg * 8) * OUT_F + ct * 16 + n;
        union { ushort u[8]; uint4 v; } pk;
        #pragma unroll
        for (int j = 0; j < 8; ++j) pk.u[j] = f2bf(base[(size_t)j * OUT_F]);
        ((uint4*)Wpk)[gid] = pk.v;
    } else {
        const int i = (blockIdx.x - 9) * 256 + tid;
        if (i < N_NODES / 4) outdeg4[i] = (int4){0, 0, 0, 0};
    }
}

// ---------------------------------------------------------------------------
// 1) fused: three roles overlapped, 32.9 KB LDS -> 4 blocks/CU (was 2).
//    bi<800: odd=partA(bi>>1), even=gemm(bi>>1);
//    bi in [800,1024): odd=hist((bi-800)>>1), even=gemm(400+((bi-800)>>1));
//    bi>=1024: gemm(bi-512).
//    gemm role: ONE BM=32 tile per 512-thread block (8 waves; wave w:
//    rowHalf=w&1, col-tile=w>>1, 8 MFMAs).
// ---------------------------------------------------------------------------
__global__ __launch_bounds__(512) void fused_kernel(const int* __restrict__ src,
                                                    const int* __restrict__ dst,
                                                    int* __restrict__ bcntD,
                                                    uint* __restrict__ pairsD,
                                                    int* __restrict__ outdeg,
                                                    const float* __restrict__ feat,
                                                    const ushort* __restrict__ Wpk,
                                                    ushort* __restrict__ h) {
    __shared__ __align__(16) char smem[33664];
    const int bi = blockIdx.x;
    const int tid = threadIdx.x;

    if (bi < 2 * PARTA_BLOCKS && (bi & 1)) {
        // ---------------- partA role (dst path only, 26.9 KB) ---------------
        int2* ed    = (int2*)smem;                    // 16000
        uint* stgD  = (uint*)(smem + 16000);          //  8000 -> 24000
        int* lcntD  = (int*)(smem + 24000);           //  1024 -> 25024
        int* ldofD  = (int*)(smem + 25024);           //  1024 -> 26048
        int* lbaseD = (int*)(smem + 26048);           //   784 -> 26832
        int* wtotD  = (int*)(smem + 26832);           //    16
        const int id = bi >> 1;
        const int n4 = EPB / 4;   // 500

        for (int i = tid; i < 256; i += 512) lcntD[i] = 0;
        __syncthreads();

        const int4* t4 = (const int4*)(dst + (size_t)id * EPB);
        const int4* s4 = (const int4*)(src + (size_t)id * EPB);
        for (int i = tid; i < n4; i += 512) {
            const int4 d = t4[i];
            const int4 s = s4[i];
            ed[4 * i + 0] = (int2){d.x, s.x};
            ed[4 * i + 1] = (int2){d.y, s.y};
            ed[4 * i + 2] = (int2){d.z, s.z};
            ed[4 * i + 3] = (int2){d.w, s.w};
            atomicAdd(&lcntD[d.x >> 8], 1);
            atomicAdd(&lcntD[d.y >> 8], 1);
            atomicAdd(&lcntD[d.z >> 8], 1);
            atomicAdd(&lcntD[d.w >> 8], 1);
        }
        __syncthreads();

        for (int i = tid; i < NB; i += 512) {
            const int cD = lcntD[i];
            lbaseD[i] = cD ? atomicAdd(&bcntD[i], cD) : 0;
        }

        if (tid < 256) {
            const int lane = tid & 63;
            const int wave = tid >> 6;
            const int vD = lcntD[tid];
            int iD = vD;
            #pragma unroll
            for (int d = 1; d < 64; d <<= 1) {
                const int uD = __shfl_up(iD, d, 64);
                if (lane >= d) iD += uD;
            }
            if (lane == 63) wtotD[wave] = iD;
            ldofD[tid] = iD - vD;
        }
        __syncthreads();
        if (tid < 256) {
            const int wave = tid >> 6;
            int woD = 0;
            #pragma unroll
            for (int w = 0; w < 4; ++w)
                if (w < wave) woD += wtotD[w];
            ldofD[tid] += woD;
            lcntD[tid] = 0;      // reuse as cursor
        }
        __syncthreads();

        for (int i = tid; i < EPB; i += 512) {
            const int2 e = ed[i];
            const int bx = e.x >> 8;
            const int pos = atomicAdd(&lcntD[bx], 1);
            stgD[ldofD[bx] + pos] =
                ((uint)bx << 24) | ((uint)(e.x & 255) << 16) | (uint)e.y;
        }
        __syncthreads();

        for (int i = tid; i < EPB; i += 512) {
            const uint pv = stgD[i];
            const int bD = (int)(pv >> 24);
            pairsD[(size_t)bD * CAP + lbaseD[bD] + (i - ldofD[bD])] = pv & 0xFFFFFFu;
        }
    } else if (bi >= 2 * PARTA_BLOCKS && bi < 2 * PARTA_BLOCKS + 2 * HIST_BLOCKS
               && (bi & 1)) {
        // ---------------- hist role: outdeg LDS histogram (32.8 KB) ---------
        int* cnt = (int*)smem;   // 32768 B
        const int id = (bi - 2 * PARTA_BLOCKS) >> 1;   // 0..111
        const int chunk = id >> 4;                     // 0..6
        const int slice = id & 15;
        const int base = chunk * HIST_CHUNK;

        for (int i = tid; i < HIST_CHUNK; i += 512) cnt[i] = 0;
        __syncthreads();

        const int4* s4 = (const int4*)(src + (size_t)slice * (N_EDGES / 16));
        for (int i = tid; i < (N_EDGES / 16) / 4; i += 512) {
            const int4 v = s4[i];
            int r;
            r = v.x - base; if ((unsigned)r < (unsigned)HIST_CHUNK) atomicAdd(&cnt[r], 1);
            r = v.y - base; if ((unsigned)r < (unsigned)HIST_CHUNK) atomicAdd(&cnt[r], 1);
            r = v.z - base; if ((unsigned)r < (unsigned)HIST_CHUNK) atomicAdd(&cnt[r], 1);
            r = v.w - base; if ((unsigned)r < (unsigned)HIST_CHUNK) atomicAdd(&cnt[r], 1);
        }
        __syncthreads();

        for (int i = tid; i < HIST_CHUNK; i += 512) {
            const int c = cnt[i];
            if (c && base + i < N_NODES) atomicAdd(&outdeg[base + i], c);
        }
    } else {
        // ---------------- gemm role: ONE BM=32 tile, 8 waves ----------------
        const int id = (bi < 2 * PARTA_BLOCKS) ? (bi >> 1)
                     : (bi < 2 * PARTA_BLOCKS + 2 * HIST_BLOCKS)
                         ? (PARTA_BLOCKS + ((bi - 2 * PARTA_BLOCKS) >> 1))
                         : (bi - PARTA_BLOCKS - HIST_BLOCKS);
        const int lane = tid & 63;
        const int wave = tid >> 6;           // 0..7
        const int m = lane & 15;
        const int g = lane >> 4;
        const int rowBase = id * GEMM_BM;
        float* ftile = (float*)smem;         // 32 KB
        const char* fb = (const char*)feat;

        // stage 32 rows: 4 iterations x 8 waves x 1 KB
        #pragma unroll
        for (int it = 0; it < 4; ++it) {
            const int R = it * 8 + wave;                  // tile row 0..31
            const int off = (lane * 16) ^ ((R & 7) << 4); // swizzled src chunk
            int grow = rowBase + R;
            if (grow >= N_NODES) grow = N_NODES - 1;      // clamp (dup row)
            __builtin_amdgcn_global_load_lds(
                (const __attribute__((address_space(1))) void*)(fb + ((size_t)grow << 10) + off),
                (__attribute__((address_space(3))) void*)((char*)ftile + it * 8192 + wave * 1024),
                16, 0, 0);
        }
        __syncthreads();

        const int rowHalf = wave & 1;        // rows 0-15 / 16-31
        const int ct = wave >> 1;            // col tile 0..3 (16 cols each)

        f32x4 acc = (f32x4){0.f, 0.f, 0.f, 0.f};

        const int Rr = rowHalf * 16 + m;     // A-frag row within tile
        const int swz = (Rr & 7) << 4;
        const char* rowb = (const char*)ftile + (Rr << 10);
        const bf16x8* wp = (const bf16x8*)Wpk;

        #pragma unroll
        for (int step = 0; step < 8; ++step) {
            const int kb = step * 128 + g * 32;
            const float4 a0 = *(const float4*)(rowb + (kb ^ swz));
            const float4 a1 = *(const float4*)(rowb + ((kb + 16) ^ swz));
            bf16x8 aa;
            aa[0] = (short)f2bf(a0.x); aa[1] = (short)f2bf(a0.y);
            aa[2] = (short)f2bf(a0.z); aa[3] = (short)f2bf(a0.w);
            aa[4] = (short)f2bf(a1.x); aa[5] = (short)f2bf(a1.y);
            aa[6] = (short)f2bf(a1.z); aa[7] = (short)f2bf(a1.w);
            acc = __builtin_amdgcn_mfma_f32_16x16x32_bf16(
                aa, wp[(step * 4 + ct) * 64 + lane], acc, 0, 0, 0);
        }

        // C-frag: col = ct*16 + m, row = rowBase + rowHalf*16 + g*4 + j
        #pragma unroll
        for (int j = 0; j < 4; ++j) {
            const int row = rowBase + rowHalf * 16 + g * 4 + j;
            if (row < N_NODES)
                h[(size_t)row * OUT_F + ct * 16 + m] = f2bf(acc[j]);
        }
    }
}

// ---------------------------------------------------------------------------
// 2) bucket: dst sort only; writes normS (contiguous outdeg read) + packed
//    ptrdeg = (bb*CAP + ex) | (deg << 21).
// ---------------------------------------------------------------------------
__global__ __launch_bounds__(1024) void bucket_kernel(const int* __restrict__ outdeg,
                                                      float* __restrict__ normS,
                                                      const uint* __restrict__ pairsD,
                                                      const int* __restrict__ bcntD,
                                                      uint* __restrict__ ptrdeg,
                                                      ushort* __restrict__ sorted_src) {
    __shared__ int cnt[BKT];
    __shared__ int loff[BKT];
    __shared__ int wtot[4];
    const int bb = blockIdx.x;
    const int tid = threadIdx.x;
    const int node = bb * BKT + tid;   // valid meaning only for tid<256

    if (tid < BKT) {
        cnt[tid] = 0;
        if (node < N_NODES)
            normS[node] = rsqrtf(fmaxf((float)outdeg[node], 1.0f));
    }
    __syncthreads();
    const int nD = bcntD[bb];
    const uint* pb = pairsD + (size_t)bb * CAP;
    for (int i = tid; i < nD; i += 1024) atomicAdd(&cnt[(pb[i] >> 16) & 255u], 1);
    __syncthreads();

    // scan on waves 0-3
    if (tid < BKT) {
        const int lane = tid & 63;
        const int wave = tid >> 6;
        const int v = cnt[tid];
        int incl = v;
        #pragma unroll
        for (int d = 1; d < 64; d <<= 1) {
            int u = __shfl_up(incl, d, 64);
            if (lane >= d) incl += u;
        }
        if (lane == 63) wtot[wave] = incl;
        loff[tid] = incl - v;            // temp: intra-wave exclusive
    }
    __syncthreads();
    if (tid < BKT) {
        const int wave = tid >> 6;
        int woff = 0;
        #pragma unroll
        for (int w = 0; w < 4; ++w)
            if (w < wave) woff += wtot[w];
        const int ex = woff + loff[tid];
        loff[tid] = ex;
        const int v = cnt[tid];
        cnt[tid] = 0;                    // reuse as per-local cursor
        if (node < N_NODES)
            ptrdeg[node] = (uint)(bb * CAP + ex) | ((uint)v << 21);
    }
    __syncthreads();

    for (int i = tid; i < nD; i += 1024) {
        const uint p = pb[i];
        const int local = (int)((p >> 16) & 255u);
        const int pos = atomicAdd(&cnt[local], 1);
        sorted_src[(size_t)bb * CAP + loff[local] + pos] = (ushort)(p & 0xFFFFu);
    }
}

// ---------------------------------------------------------------------------
// 3) Gather + epilogue: one wave per dst node, quarter-wave per edge,
//    gathered rows scaled by normS[src]; packed ptrdeg.
// ---------------------------------------------------------------------------
__global__ __launch_bounds__(256) void gather_kernel(const uint* __restrict__ ptrdeg,
                                                     const ushort* __restrict__ sorted_src,
                                                     const float* __restrict__ normS,
                                                     const ushort* __restrict__ h,
                                                     const float* __restrict__ b,
                                                     float* __restrict__ out) {
    const int lane = threadIdx.x & 63;
    const int q = lane & 15;           // col group: cols q*4 .. q*4+3
    const int g = lane >> 4;           // edge slot 0..3
    int nid = (int)((blockIdx.x * (size_t)blockDim.x + threadIdx.x) >> 6);
    if (nid >= N_NODES) return;
    nid = __builtin_amdgcn_readfirstlane(nid);

    const uint pd = ptrdeg[nid];
    const int beg = (int)(pd & 0x1FFFFFu);
    const int deg = (int)(pd >> 21);

    float a0 = 0.f, a1 = 0.f, a2 = 0.f, a3 = 0.f;
    const int nfull = deg >> 2;
    int e = beg + g;
    #pragma unroll 4
    for (int i = 0; i < nfull; ++i) {
        const int s = (int)sorted_src[e];
        e += 4;
        const float ns = normS[s];
        const uint2 v = *(const uint2*)(h + (size_t)s * OUT_F + q * 4);
        a0 = fmaf(ns, bf_lo(v.x), a0); a1 = fmaf(ns, bf_hi(v.x), a1);
        a2 = fmaf(ns, bf_lo(v.y), a2); a3 = fmaf(ns, bf_hi(v.y), a3);
    }
    const int rem = deg & 3;
    if (g < rem) {
        const int s = (int)sorted_src[beg + (deg & ~3) + g];
        const float ns = normS[s];
        const uint2 v = *(const uint2*)(h + (size_t)s * OUT_F + q * 4);
        a0 = fmaf(ns, bf_lo(v.x), a0); a1 = fmaf(ns, bf_hi(v.x), a1);
        a2 = fmaf(ns, bf_lo(v.y), a2); a3 = fmaf(ns, bf_hi(v.y), a3);
    }
    a0 += __shfl_xor(a0, 16, 64); a1 += __shfl_xor(a1, 16, 64);
    a2 += __shfl_xor(a2, 16, 64); a3 += __shfl_xor(a3, 16, 64);
    a0 += __shfl_xor(a0, 32, 64); a1 += __shfl_xor(a1, 32, 64);
    a2 += __shfl_xor(a2, 32, 64); a3 += __shfl_xor(a3, 32, 64);

    if (g == 0) {
        const float norm = rsqrtf(fmaxf((float)deg, 1.0f));
        const float4 bb = *(const float4*)(b + q * 4);
        float4 o;
        o.x = 1.0f / (1.0f + expf(-(a0 * norm + bb.x)));
        o.y = 1.0f / (1.0f + expf(-(a1 * norm + bb.y)));
        o.z = 1.0f / (1.0f + expf(-(a2 * norm + bb.z)));
        o.w = 1.0f / (1.0f + expf(-(a3 * norm + bb.w)));
        *(float4*)(out + (size_t)nid * OUT_F + q * 4) = o;
    }
}

// ---------------------------------------------------------------------------
extern "C" void kernel_launch(void* const* d_in, const int* in_sizes, int n_in,
                              void* d_out, int out_size, void* d_ws, size_t ws_size,
                              hipStream_t stream) {
    const float* feat = (const float*)d_in[0];
    const int* src    = (const int*)d_in[1];
    const int* dst    = (const int*)d_in[2];
    const float* W    = (const float*)d_in[3];
    const float* b    = (const float*)d_in[4];
    float* out = (float*)d_out;

    char* ws = (char*)d_ws;
    size_t off = 0;
    ushort* h = (ushort*)(ws + off);        off += (size_t)N_NODES * OUT_F * 2;  // 6.4 MB
    float* normS = (float*)(ws + off);      off += (size_t)N_NODES * 4;          // 200 KB
    uint* ptrdeg = (uint*)(ws + off);       off += (size_t)N_NODES * 4;          // 200 KB
    int* outdeg = (int*)(ws + off);         off += (size_t)N_NODES * 4;          // 200 KB
    int* bcntD = (int*)(ws + off);          off += (size_t)NB * 4 + 16;
    ushort* Wpk = (ushort*)(ws + off);      off += (size_t)IN_F * OUT_F * 2;     // 32 KB
    uint* pairsD = (uint*)(ws + off);       off += (size_t)NB * CAP * 4;         // 4.8 MB
    ushort* sorted_src = (ushort*)(ws + off); off += (size_t)NB * CAP * 2;       // 2.4 MB

    prep_kernel<<<9 + (N_NODES / 4 + 255) / 256, 256, 0, stream>>>(
        bcntD, W, Wpk, (int4*)outdeg);

    fused_kernel<<<2 * PARTA_BLOCKS + 2 * HIST_BLOCKS +
                       (GEMM_TILES - PARTA_BLOCKS - HIST_BLOCKS),
                   512, 0, stream>>>(
        src, dst, bcntD, pairsD, outdeg, feat, Wpk, h);

    bucket_kernel<<<NB, 1024, 0, stream>>>(outdeg, normS,
                                           pairsD, bcntD, ptrdeg, sorted_src);

    gather_kernel<<<(N_NODES * 64 + 255) / 256, 256, 0, stream>>>(
        ptrdeg, sorted_src, normS, h, b, out);
}

// Round 24
// 67.487 us; speedup vs baseline: 1.0340x; 1.0340x over previous
//
#include <hip/hip_runtime.h>
#include <hip/hip_bf16.h>
#include <math.h>

#define N_NODES 50000
#define N_EDGES 800000
#define IN_F 256
#define OUT_F 64

#define BKT 128            // nodes per bucket (was 256: bucket occupancy 2x)
#define NB 391             // ceil(50000/128)
#define CAP 3072           // fixed per-bucket capacity (mean 2048, sigma 45)
#define PARTA_BLOCKS 400   // 800000/400 = 2000 edges/block
#define EPB (N_EDGES / PARTA_BLOCKS)   // 2000
#define GEMM_BM 32
#define GEMM_BLOCKS 782    // two BM=32 tiles per 512-thread block role
#define HIST_CHUNK 12500   // outdeg hist: 4 chunks x 16 slices = 64 blocks
#define HIST_BLOCKS 64

typedef __attribute__((ext_vector_type(8))) short bf16x8;
typedef __attribute__((ext_vector_type(4))) float f32x4;

__device__ __forceinline__ ushort f2bf(float x) {
    __hip_bfloat16 b = __float2bfloat16(x);   // RNE
    return *reinterpret_cast<ushort*>(&b);
}
__device__ __forceinline__ float bf_lo(uint v) { return __uint_as_float(v << 16); }
__device__ __forceinline__ float bf_hi(uint v) { return __uint_as_float(v & 0xffff0000u); }

// ---------------------------------------------------------------------------
// 0) prep: block 0 zeros bcntD; blocks 1..8 pack W into bf16 MFMA B-frag
//    layout; blocks 9+ zero outdeg (12500 int4).
// ---------------------------------------------------------------------------
__global__ __launch_bounds__(256) void prep_kernel(int* __restrict__ bcntD,
                                                   const float* __restrict__ W,
                                                   ushort* __restrict__ Wpk,
                                                   int4* __restrict__ outdeg4) {
    const int tid = threadIdx.x;
    if (blockIdx.x == 0) {
        for (int i = tid; i < NB; i += 256) bcntD[i] = 0;
    } else if (blockIdx.x < 9) {
        const int gid = (blockIdx.x - 1) * 256 + tid;   // 0..2047
        const int lane = gid & 63;
        const int ct = (gid >> 6) & 3;
        const int step = gid >> 8;
        const int kg = lane >> 4;
        const int n = lane & 15;
        const float* base = W + (size_t)(step * 32 + kg * 8) * OUT_F + ct * 16 + n;
        union { ushort u[8]; uint4 v; } pk;
        #pragma unroll
        for (int j = 0; j < 8; ++j) pk.u[j] = f2bf(base[(size_t)j * OUT_F]);
        ((uint4*)Wpk)[gid] = pk.v;
    } else {
        const int i = (blockIdx.x - 9) * 256 + tid;
        if (i < N_NODES / 4) outdeg4[i] = (int4){0, 0, 0, 0};
    }
}

// ---------------------------------------------------------------------------
// 1) fused: three roles overlapped (round-22 structure, 68.0us) —
//    partA (dst-only bucket-partition), hist (outdeg LDS histogram),
//    gemm (global_load_lds + MFMA, two BM=32 tiles per 512-thread block).
//    bi<800: odd=partA(bi>>1), even=gemm(bi>>1);
//    bi in [800,928): odd=hist((bi-800)>>1), even=gemm(400+((bi-800)>>1));
//    bi>=928: gemm(bi-464).
//    Bucket id now 9 bits (NB=391): stgD = (bx<<23)|(local&127)<<16|src.
// ---------------------------------------------------------------------------
__global__ __launch_bounds__(512) void fused_kernel(const int* __restrict__ src,
                                                    const int* __restrict__ dst,
                                                    int* __restrict__ bcntD,
                                                    uint* __restrict__ pairsD,
                                                    int* __restrict__ outdeg,
                                                    const float* __restrict__ feat,
                                                    const ushort* __restrict__ Wpk,
                                                    ushort* __restrict__ h) {
    __shared__ __align__(16) char smem[65536];
    const int bi = blockIdx.x;
    const int tid = threadIdx.x;

    if (bi < 2 * PARTA_BLOCKS && (bi & 1)) {
        // ---------------- partA role (dst path only) ------------------------
        int2* ed    = (int2*)smem;                    // 16000
        uint* stgD  = (uint*)(smem + 16000);          //  8000 -> 24000
        int* lcntD  = (int*)(smem + 24000);           //  2048 -> 26048
        int* ldofD  = (int*)(smem + 26048);           //  2048 -> 28096
        int* lbaseD = (int*)(smem + 28096);           //  2048 -> 30144
        int* wtotD  = (int*)(smem + 30144);           //    32
        const int id = bi >> 1;
        const int n4 = EPB / 4;   // 500

        for (int i = tid; i < NB; i += 512) lcntD[i] = 0;
        __syncthreads();

        const int4* t4 = (const int4*)(dst + (size_t)id * EPB);
        const int4* s4 = (const int4*)(src + (size_t)id * EPB);
        for (int i = tid; i < n4; i += 512) {
            const int4 d = t4[i];
            const int4 s = s4[i];
            ed[4 * i + 0] = (int2){d.x, s.x};
            ed[4 * i + 1] = (int2){d.y, s.y};
            ed[4 * i + 2] = (int2){d.z, s.z};
            ed[4 * i + 3] = (int2){d.w, s.w};
            atomicAdd(&lcntD[d.x >> 7], 1);
            atomicAdd(&lcntD[d.y >> 7], 1);
            atomicAdd(&lcntD[d.z >> 7], 1);
            atomicAdd(&lcntD[d.w >> 7], 1);
        }
        __syncthreads();

        for (int i = tid; i < NB; i += 512) {
            const int cD = lcntD[i];
            lbaseD[i] = cD ? atomicAdd(&bcntD[i], cD) : 0;
        }
        __syncthreads();

        // 512-wide exclusive scan (8 waves) over NB=391 counters
        {
            const int lane = tid & 63;
            const int wave = tid >> 6;
            const int vD = (tid < NB) ? lcntD[tid] : 0;
            int iD = vD;
            #pragma unroll
            for (int d = 1; d < 64; d <<= 1) {
                const int uD = __shfl_up(iD, d, 64);
                if (lane >= d) iD += uD;
            }
            if (lane == 63) wtotD[wave] = iD;
            __syncthreads();
            int woD = 0;
            #pragma unroll
            for (int w = 0; w < 8; ++w)
                if (w < wave) woD += wtotD[w];
            if (tid < NB) {
                ldofD[tid] = woD + iD - vD;
                lcntD[tid] = 0;      // reuse as cursor
            }
        }
        __syncthreads();

        for (int i = tid; i < EPB; i += 512) {
            const int2 e = ed[i];
            const int bx = e.x >> 7;
            const int pos = atomicAdd(&lcntD[bx], 1);
            stgD[ldofD[bx] + pos] =
                ((uint)bx << 23) | ((uint)(e.x & 127) << 16) | (uint)e.y;
        }
        __syncthreads();

        for (int i = tid; i < EPB; i += 512) {
            const uint pv = stgD[i];
            const int bD = (int)(pv >> 23);
            pairsD[(size_t)bD * CAP + lbaseD[bD] + (i - ldofD[bD])] = pv & 0x7FFFFFu;
        }
    } else if (bi >= 2 * PARTA_BLOCKS && bi < 2 * PARTA_BLOCKS + 2 * HIST_BLOCKS
               && (bi & 1)) {
        // ---------------- hist role: outdeg LDS histogram -------------------
        int* cnt = (int*)smem;   // 50000 B
        const int id = (bi - 2 * PARTA_BLOCKS) >> 1;   // 0..63
        const int chunk = id >> 4;
        const int slice = id & 15;
        const int base = chunk * HIST_CHUNK;

        for (int i = tid; i < HIST_CHUNK; i += 512) cnt[i] = 0;
        __syncthreads();

        const int4* s4 = (const int4*)(src + (size_t)slice * (N_EDGES / 16));
        for (int i = tid; i < (N_EDGES / 16) / 4; i += 512) {
            const int4 v = s4[i];
            int r;
            r = v.x - base; if ((unsigned)r < (unsigned)HIST_CHUNK) atomicAdd(&cnt[r], 1);
            r = v.y - base; if ((unsigned)r < (unsigned)HIST_CHUNK) atomicAdd(&cnt[r], 1);
            r = v.z - base; if ((unsigned)r < (unsigned)HIST_CHUNK) atomicAdd(&cnt[r], 1);
            r = v.w - base; if ((unsigned)r < (unsigned)HIST_CHUNK) atomicAdd(&cnt[r], 1);
        }
        __syncthreads();

        for (int i = tid; i < HIST_CHUNK; i += 512) {
            const int c = cnt[i];
            if (c) atomicAdd(&outdeg[base + i], c);
        }
    } else {
        // ---------------- gemm role: two BM=32 tiles ------------------------
        const int id = (bi < 2 * PARTA_BLOCKS) ? (bi >> 1)
                     : (bi < 2 * PARTA_BLOCKS + 2 * HIST_BLOCKS)
                         ? (PARTA_BLOCKS + ((bi - 2 * PARTA_BLOCKS) >> 1))
                         : (bi - PARTA_BLOCKS - HIST_BLOCKS);
        const int half = tid >> 8;           // 0/1: which tile
        const int t = tid & 255;
        const int lane = t & 63;
        const int wave = t >> 6;             // 0..3 within half
        const int m = lane & 15;
        const int g = lane >> 4;
        const int rowBase = (id * 2 + half) * GEMM_BM;
        float* ftile = (float*)(smem + (size_t)half * 32768);
        const char* fb = (const char*)feat;

        #pragma unroll
        for (int it = 0; it < 8; ++it) {
            const int R = it * 4 + wave;                  // tile row 0..31
            const int off = (lane * 16) ^ ((R & 7) << 4); // swizzled src chunk
            int grow = rowBase + R;
            if (grow >= N_NODES) grow = N_NODES - 1;      // clamp (dup row)
            __builtin_amdgcn_global_load_lds(
                (const __attribute__((address_space(1))) void*)(fb + ((size_t)grow << 10) + off),
                (__attribute__((address_space(3))) void*)((char*)ftile + it * 4096 + wave * 1024),
                16, 0, 0);
        }
        __syncthreads();

        const int rowHalf = wave & 1;
        const int colHalf = wave >> 1;

        f32x4 acc[2];
        acc[0] = (f32x4){0.f, 0.f, 0.f, 0.f};
        acc[1] = (f32x4){0.f, 0.f, 0.f, 0.f};

        const int Rr = rowHalf * 16 + m;
        const int swz = (Rr & 7) << 4;
        const char* rowb = (const char*)ftile + (Rr << 10);
        const bf16x8* wp = (const bf16x8*)Wpk;

        #pragma unroll
        for (int step = 0; step < 8; ++step) {
            const int kb = step * 128 + g * 32;
            const float4 a0 = *(const float4*)(rowb + (kb ^ swz));
            const float4 a1 = *(const float4*)(rowb + ((kb + 16) ^ swz));
            bf16x8 aa;
            aa[0] = (short)f2bf(a0.x); aa[1] = (short)f2bf(a0.y);
            aa[2] = (short)f2bf(a0.z); aa[3] = (short)f2bf(a0.w);
            aa[4] = (short)f2bf(a1.x); aa[5] = (short)f2bf(a1.y);
            aa[6] = (short)f2bf(a1.z); aa[7] = (short)f2bf(a1.w);
            #pragma unroll
            for (int ct = 0; ct < 2; ++ct)
                acc[ct] = __builtin_amdgcn_mfma_f32_16x16x32_bf16(
                    aa, wp[(step * 4 + colHalf * 2 + ct) * 64 + lane], acc[ct], 0, 0, 0);
        }

        #pragma unroll
        for (int j = 0; j < 4; ++j) {
            const int row = rowBase + rowHalf * 16 + g * 4 + j;
            if (row < N_NODES) {
                #pragma unroll
                for (int ct = 0; ct < 2; ++ct)
                    h[(size_t)row * OUT_F + colHalf * 32 + ct * 16 + m] = f2bf(acc[ct][j]);
            }
        }
    }
}

// ---------------------------------------------------------------------------
// 2) bucket: dst sort only, 391 blocks (2x occupancy of BKT=256 version).
//    Writes normS (contiguous outdeg read) + packed ptrdeg.
// ---------------------------------------------------------------------------
__global__ __launch_bounds__(1024) void bucket_kernel(const int* __restrict__ outdeg,
                                                      float* __restrict__ normS,
                                                      const uint* __restrict__ pairsD,
                                                      const int* __restrict__ bcntD,
                                                      uint* __restrict__ ptrdeg,
                                                      ushort* __restrict__ sorted_src) {
    __shared__ int cnt[BKT];
    __shared__ int loff[BKT];
    __shared__ int wtot[2];
    const int bb = blockIdx.x;
    const int tid = threadIdx.x;
    const int node = bb * BKT + tid;   // valid meaning only for tid<128

    if (tid < BKT) {
        cnt[tid] = 0;
        if (node < N_NODES)
            normS[node] = rsqrtf(fmaxf((float)outdeg[node], 1.0f));
    }
    __syncthreads();
    const int nD = bcntD[bb];
    const uint* pb = pairsD + (size_t)bb * CAP;
    for (int i = tid; i < nD; i += 1024) atomicAdd(&cnt[(pb[i] >> 16) & 127u], 1);
    __syncthreads();

    // scan on waves 0-1 (128 counters)
    if (tid < BKT) {
        const int lane = tid & 63;
        const int wave = tid >> 6;
        const int v = cnt[tid];
        int incl = v;
        #pragma unroll
        for (int d = 1; d < 64; d <<= 1) {
            int u = __shfl_up(incl, d, 64);
            if (lane >= d) incl += u;
        }
        if (lane == 63) wtot[wave] = incl;
        loff[tid] = incl - v;            // temp: intra-wave exclusive
    }
    __syncthreads();
    if (tid < BKT) {
        const int wave = tid >> 6;
        const int ex = ((wave == 1) ? wtot[0] : 0) + loff[tid];
        loff[tid] = ex;
        const int v = cnt[tid];
        cnt[tid] = 0;                    // reuse as per-local cursor
        if (node < N_NODES)
            ptrdeg[node] = (uint)(bb * CAP + ex) | ((uint)v << 21);
    }
    __syncthreads();

    for (int i = tid; i < nD; i += 1024) {
        const uint p = pb[i];
        const int local = (int)((p >> 16) & 127u);
        const int pos = atomicAdd(&cnt[local], 1);
        sorted_src[(size_t)bb * CAP + loff[local] + pos] = (ushort)(p & 0xFFFFu);
    }
}

// ---------------------------------------------------------------------------
// 3) Gather + epilogue: one wave per dst node, quarter-wave per edge,
//    gathered rows scaled by normS[src]; packed ptrdeg.
// ---------------------------------------------------------------------------
__global__ __launch_bounds__(256) void gather_kernel(const uint* __restrict__ ptrdeg,
                                                     const ushort* __restrict__ sorted_src,
                                                     const float* __restrict__ normS,
                                                     const ushort* __restrict__ h,
                                                     const float* __restrict__ b,
                                                     float* __restrict__ out) {
    const int lane = threadIdx.x & 63;
    const int q = lane & 15;           // col group: cols q*4 .. q*4+3
    const int g = lane >> 4;           // edge slot 0..3
    int nid = (int)((blockIdx.x * (size_t)blockDim.x + threadIdx.x) >> 6);
    if (nid >= N_NODES) return;
    nid = __builtin_amdgcn_readfirstlane(nid);

    const uint pd = ptrdeg[nid];
    const int beg = (int)(pd & 0x1FFFFFu);
    const int deg = (int)(pd >> 21);

    float a0 = 0.f, a1 = 0.f, a2 = 0.f, a3 = 0.f;
    const int nfull = deg >> 2;
    int e = beg + g;
    #pragma unroll 4
    for (int i = 0; i < nfull; ++i) {
        const int s = (int)sorted_src[e];
        e += 4;
        const float ns = normS[s];
        const uint2 v = *(const uint2*)(h + (size_t)s * OUT_F + q * 4);
        a0 = fmaf(ns, bf_lo(v.x), a0); a1 = fmaf(ns, bf_hi(v.x), a1);
        a2 = fmaf(ns, bf_lo(v.y), a2); a3 = fmaf(ns, bf_hi(v.y), a3);
    }
    const int rem = deg & 3;
    if (g < rem) {
        const int s = (int)sorted_src[beg + (deg & ~3) + g];
        const float ns = normS[s];
        const uint2 v = *(const uint2*)(h + (size_t)s * OUT_F + q * 4);
        a0 = fmaf(ns, bf_lo(v.x), a0); a1 = fmaf(ns, bf_hi(v.x), a1);
        a2 = fmaf(ns, bf_lo(v.y), a2); a3 = fmaf(ns, bf_hi(v.y), a3);
    }
    a0 += __shfl_xor(a0, 16, 64); a1 += __shfl_xor(a1, 16, 64);
    a2 += __shfl_xor(a2, 16, 64); a3 += __shfl_xor(a3, 16, 64);
    a0 += __shfl_xor(a0, 32, 64); a1 += __shfl_xor(a1, 32, 64);
    a2 += __shfl_xor(a2, 32, 64); a3 += __shfl_xor(a3, 32, 64);

    if (g == 0) {
        const float norm = rsqrtf(fmaxf((float)deg, 1.0f));
        const float4 bb = *(const float4*)(b + q * 4);
        float4 o;
        o.x = 1.0f / (1.0f + expf(-(a0 * norm + bb.x)));
        o.y = 1.0f / (1.0f + expf(-(a1 * norm + bb.y)));
        o.z = 1.0f / (1.0f + expf(-(a2 * norm + bb.z)));
        o.w = 1.0f / (1.0f + expf(-(a3 * norm + bb.w)));
        *(float4*)(out + (size_t)nid * OUT_F + q * 4) = o;
    }
}

// ---------------------------------------------------------------------------
extern "C" void kernel_launch(void* const* d_in, const int* in_sizes, int n_in,
                              void* d_out, int out_size, void* d_ws, size_t ws_size,
                              hipStream_t stream) {
    const float* feat = (const float*)d_in[0];
    const int* src    = (const int*)d_in[1];
    const int* dst    = (const int*)d_in[2];
    const float* W    = (const float*)d_in[3];
    const float* b    = (const float*)d_in[4];
    float* out = (float*)d_out;

    char* ws = (char*)d_ws;
    size_t off = 0;
    ushort* h = (ushort*)(ws + off);        off += (size_t)N_NODES * OUT_F * 2;  // 6.4 MB
    float* normS = (float*)(ws + off);      off += (size_t)N_NODES * 4;          // 200 KB
    uint* ptrdeg = (uint*)(ws + off);       off += (size_t)N_NODES * 4;          // 200 KB
    int* outdeg = (int*)(ws + off);         off += (size_t)N_NODES * 4;          // 200 KB
    int* bcntD = (int*)(ws + off);          off += (size_t)NB * 4 + 16;
    ushort* Wpk = (ushort*)(ws + off);      off += (size_t)IN_F * OUT_F * 2;     // 32 KB
    uint* pairsD = (uint*)(ws + off);       off += (size_t)NB * CAP * 4;         // 4.8 MB
    ushort* sorted_src = (ushort*)(ws + off); off += (size_t)NB * CAP * 2;       // 2.4 MB

    prep_kernel<<<9 + (N_NODES / 4 + 255) / 256, 256, 0, stream>>>(
        bcntD, W, Wpk, (int4*)outdeg);

    fused_kernel<<<PARTA_BLOCKS + HIST_BLOCKS + GEMM_BLOCKS, 512, 0, stream>>>(
        src, dst, bcntD, pairsD, outdeg, feat, Wpk, h);

    bucket_kernel<<<NB, 1024, 0, stream>>>(outdeg, normS,
                                           pairsD, bcntD, ptrdeg, sorted_src);

    gather_kernel<<<(N_NODES * 64 + 255) / 256, 256, 0, stream>>>(
        ptrdeg, sorted_src, normS, h, b, out);
}

// Round 25
// 66.196 us; speedup vs baseline: 1.0542x; 1.0195x over previous
//
#include <hip/hip_runtime.h>
#include <hip/hip_bf16.h>
#include <math.h>

#define N_NODES 50000
#define N_EDGES 800000
#define IN_F 256
#define OUT_F 64

#define BKT 128            // nodes per bucket
#define NB 391             // ceil(50000/128)
#define CAP 3072           // fixed per-bucket capacity (mean 2048, sigma 45)
#define PARTA_BLOCKS 400   // 800000/400 = 2000 edges/block
#define EPB (N_EDGES / PARTA_BLOCKS)   // 2000
#define GEMM_BM 32
#define GEMM_BLOCKS 782    // two BM=32 tiles per 512-thread block role
#define HIST_CHUNK 12500   // outdeg hist: 4 chunks x 16 slices = 64 blocks
#define HIST_BLOCKS 64

typedef __attribute__((ext_vector_type(8))) short bf16x8;
typedef __attribute__((ext_vector_type(4))) float f32x4;

__device__ __forceinline__ ushort f2bf(float x) {
    __hip_bfloat16 b = __float2bfloat16(x);   // RNE
    return *reinterpret_cast<ushort*>(&b);
}
__device__ __forceinline__ float bf_lo(uint v) { return __uint_as_float(v << 16); }
__device__ __forceinline__ float bf_hi(uint v) { return __uint_as_float(v & 0xffff0000u); }

// ---------------------------------------------------------------------------
// 0) prep: block 0 zeros bcntD; blocks 1..8 pack W into bf16 MFMA B-frag
//    layout; blocks 9+ zero outdeg (12500 int4).
// ---------------------------------------------------------------------------
__global__ __launch_bounds__(256) void prep_kernel(int* __restrict__ bcntD,
                                                   const float* __restrict__ W,
                                                   ushort* __restrict__ Wpk,
                                                   int4* __restrict__ outdeg4) {
    const int tid = threadIdx.x;
    if (blockIdx.x == 0) {
        for (int i = tid; i < NB; i += 256) bcntD[i] = 0;
    } else if (blockIdx.x < 9) {
        const int gid = (blockIdx.x - 1) * 256 + tid;   // 0..2047
        const int lane = gid & 63;
        const int ct = (gid >> 6) & 3;
        const int step = gid >> 8;
        const int kg = lane >> 4;
        const int n = lane & 15;
        const float* base = W + (size_t)(step * 32 + kg * 8) * OUT_F + ct * 16 + n;
        union { ushort u[8]; uint4 v; } pk;
        #pragma unroll
        for (int j = 0; j < 8; ++j) pk.u[j] = f2bf(base[(size_t)j * OUT_F]);
        ((uint4*)Wpk)[gid] = pk.v;
    } else {
        const int i = (blockIdx.x - 9) * 256 + tid;
        if (i < N_NODES / 4) outdeg4[i] = (int4){0, 0, 0, 0};
    }
}

// ---------------------------------------------------------------------------
// 1) fused: three roles overlapped (round-24 config, kept) —
//    partA (dst-only bucket-partition), hist (outdeg LDS histogram),
//    gemm (global_load_lds + MFMA, two BM=32 tiles per 512-thread block).
// ---------------------------------------------------------------------------
__global__ __launch_bounds__(512) void fused_kernel(const int* __restrict__ src,
                                                    const int* __restrict__ dst,
                                                    int* __restrict__ bcntD,
                                                    uint* __restrict__ pairsD,
                                                    int* __restrict__ outdeg,
                                                    const float* __restrict__ feat,
                                                    const ushort* __restrict__ Wpk,
                                                    ushort* __restrict__ h) {
    __shared__ __align__(16) char smem[65536];
    const int bi = blockIdx.x;
    const int tid = threadIdx.x;

    if (bi < 2 * PARTA_BLOCKS && (bi & 1)) {
        // ---------------- partA role (dst path only) ------------------------
        int2* ed    = (int2*)smem;                    // 16000
        uint* stgD  = (uint*)(smem + 16000);          //  8000 -> 24000
        int* lcntD  = (int*)(smem + 24000);           //  2048 -> 26048
        int* ldofD  = (int*)(smem + 26048);           //  2048 -> 28096
        int* lbaseD = (int*)(smem + 28096);           //  2048 -> 30144
        int* wtotD  = (int*)(smem + 30144);           //    32
        const int id = bi >> 1;
        const int n4 = EPB / 4;   // 500

        for (int i = tid; i < NB; i += 512) lcntD[i] = 0;
        __syncthreads();

        const int4* t4 = (const int4*)(dst + (size_t)id * EPB);
        const int4* s4 = (const int4*)(src + (size_t)id * EPB);
        for (int i = tid; i < n4; i += 512) {
            const int4 d = t4[i];
            const int4 s = s4[i];
            ed[4 * i + 0] = (int2){d.x, s.x};
            ed[4 * i + 1] = (int2){d.y, s.y};
            ed[4 * i + 2] = (int2){d.z, s.z};
            ed[4 * i + 3] = (int2){d.w, s.w};
            atomicAdd(&lcntD[d.x >> 7], 1);
            atomicAdd(&lcntD[d.y >> 7], 1);
            atomicAdd(&lcntD[d.z >> 7], 1);
            atomicAdd(&lcntD[d.w >> 7], 1);
        }
        __syncthreads();

        for (int i = tid; i < NB; i += 512) {
            const int cD = lcntD[i];
            lbaseD[i] = cD ? atomicAdd(&bcntD[i], cD) : 0;
        }
        __syncthreads();

        // 512-wide exclusive scan (8 waves) over NB=391 counters
        {
            const int lane = tid & 63;
            const int wave = tid >> 6;
            const int vD = (tid < NB) ? lcntD[tid] : 0;
            int iD = vD;
            #pragma unroll
            for (int d = 1; d < 64; d <<= 1) {
                const int uD = __shfl_up(iD, d, 64);
                if (lane >= d) iD += uD;
            }
            if (lane == 63) wtotD[wave] = iD;
            __syncthreads();
            int woD = 0;
            #pragma unroll
            for (int w = 0; w < 8; ++w)
                if (w < wave) woD += wtotD[w];
            if (tid < NB) {
                ldofD[tid] = woD + iD - vD;
                lcntD[tid] = 0;      // reuse as cursor
            }
        }
        __syncthreads();

        for (int i = tid; i < EPB; i += 512) {
            const int2 e = ed[i];
            const int bx = e.x >> 7;
            const int pos = atomicAdd(&lcntD[bx], 1);
            stgD[ldofD[bx] + pos] =
                ((uint)bx << 23) | ((uint)(e.x & 127) << 16) | (uint)e.y;
        }
        __syncthreads();

        for (int i = tid; i < EPB; i += 512) {
            const uint pv = stgD[i];
            const int bD = (int)(pv >> 23);
            pairsD[(size_t)bD * CAP + lbaseD[bD] + (i - ldofD[bD])] = pv & 0x7FFFFFu;
        }
    } else if (bi >= 2 * PARTA_BLOCKS && bi < 2 * PARTA_BLOCKS + 2 * HIST_BLOCKS
               && (bi & 1)) {
        // ---------------- hist role: outdeg LDS histogram -------------------
        int* cnt = (int*)smem;   // 50000 B
        const int id = (bi - 2 * PARTA_BLOCKS) >> 1;   // 0..63
        const int chunk = id >> 4;
        const int slice = id & 15;
        const int base = chunk * HIST_CHUNK;

        for (int i = tid; i < HIST_CHUNK; i += 512) cnt[i] = 0;
        __syncthreads();

        const int4* s4 = (const int4*)(src + (size_t)slice * (N_EDGES / 16));
        for (int i = tid; i < (N_EDGES / 16) / 4; i += 512) {
            const int4 v = s4[i];
            int r;
            r = v.x - base; if ((unsigned)r < (unsigned)HIST_CHUNK) atomicAdd(&cnt[r], 1);
            r = v.y - base; if ((unsigned)r < (unsigned)HIST_CHUNK) atomicAdd(&cnt[r], 1);
            r = v.z - base; if ((unsigned)r < (unsigned)HIST_CHUNK) atomicAdd(&cnt[r], 1);
            r = v.w - base; if ((unsigned)r < (unsigned)HIST_CHUNK) atomicAdd(&cnt[r], 1);
        }
        __syncthreads();

        for (int i = tid; i < HIST_CHUNK; i += 512) {
            const int c = cnt[i];
            if (c) atomicAdd(&outdeg[base + i], c);
        }
    } else {
        // ---------------- gemm role: two BM=32 tiles ------------------------
        const int id = (bi < 2 * PARTA_BLOCKS) ? (bi >> 1)
                     : (bi < 2 * PARTA_BLOCKS + 2 * HIST_BLOCKS)
                         ? (PARTA_BLOCKS + ((bi - 2 * PARTA_BLOCKS) >> 1))
                         : (bi - PARTA_BLOCKS - HIST_BLOCKS);
        const int half = tid >> 8;           // 0/1: which tile
        const int t = tid & 255;
        const int lane = t & 63;
        const int wave = t >> 6;             // 0..3 within half
        const int m = lane & 15;
        const int g = lane >> 4;
        const int rowBase = (id * 2 + half) * GEMM_BM;
        float* ftile = (float*)(smem + (size_t)half * 32768);
        const char* fb = (const char*)feat;

        #pragma unroll
        for (int it = 0; it < 8; ++it) {
            const int R = it * 4 + wave;                  // tile row 0..31
            const int off = (lane * 16) ^ ((R & 7) << 4); // swizzled src chunk
            int grow = rowBase + R;
            if (grow >= N_NODES) grow = N_NODES - 1;      // clamp (dup row)
            __builtin_amdgcn_global_load_lds(
                (const __attribute__((address_space(1))) void*)(fb + ((size_t)grow << 10) + off),
                (__attribute__((address_space(3))) void*)((char*)ftile + it * 4096 + wave * 1024),
                16, 0, 0);
        }
        __syncthreads();

        const int rowHalf = wave & 1;
        const int colHalf = wave >> 1;

        f32x4 acc[2];
        acc[0] = (f32x4){0.f, 0.f, 0.f, 0.f};
        acc[1] = (f32x4){0.f, 0.f, 0.f, 0.f};

        const int Rr = rowHalf * 16 + m;
        const int swz = (Rr & 7) << 4;
        const char* rowb = (const char*)ftile + (Rr << 10);
        const bf16x8* wp = (const bf16x8*)Wpk;

        #pragma unroll
        for (int step = 0; step < 8; ++step) {
            const int kb = step * 128 + g * 32;
            const float4 a0 = *(const float4*)(rowb + (kb ^ swz));
            const float4 a1 = *(const float4*)(rowb + ((kb + 16) ^ swz));
            bf16x8 aa;
            aa[0] = (short)f2bf(a0.x); aa[1] = (short)f2bf(a0.y);
            aa[2] = (short)f2bf(a0.z); aa[3] = (short)f2bf(a0.w);
            aa[4] = (short)f2bf(a1.x); aa[5] = (short)f2bf(a1.y);
            aa[6] = (short)f2bf(a1.z); aa[7] = (short)f2bf(a1.w);
            #pragma unroll
            for (int ct = 0; ct < 2; ++ct)
                acc[ct] = __builtin_amdgcn_mfma_f32_16x16x32_bf16(
                    aa, wp[(step * 4 + colHalf * 2 + ct) * 64 + lane], acc[ct], 0, 0, 0);
        }

        #pragma unroll
        for (int j = 0; j < 4; ++j) {
            const int row = rowBase + rowHalf * 16 + g * 4 + j;
            if (row < N_NODES) {
                #pragma unroll
                for (int ct = 0; ct < 2; ++ct)
                    h[(size_t)row * OUT_F + colHalf * 32 + ct * 16 + m] = f2bf(acc[ct][j]);
            }
        }
    }
}

// ---------------------------------------------------------------------------
// 2) buckgather: merged bucket-sort + gather + epilogue. One block per
//    bucket (1024 thr). Sort lands in LDS (never global); then 16 waves x
//    8 nodes gather with quarter-wave per edge, normS computed on the fly
//    from outdeg (identical value to the old table). Eliminates sorted_src
//    / ptrdeg / normS round-trips and one launch; sort of block k+1
//    overlaps gather of block k.
// ---------------------------------------------------------------------------
__global__ __launch_bounds__(1024) void buckgather_kernel(const int* __restrict__ outdeg,
                                                          const uint* __restrict__ pairsD,
                                                          const int* __restrict__ bcntD,
                                                          const ushort* __restrict__ h,
                                                          const float* __restrict__ b,
                                                          float* __restrict__ out) {
    __shared__ ushort sorted[CAP];      // 6 KB
    __shared__ int cnt[BKT];
    __shared__ int loff[BKT];
    __shared__ int degL[BKT];
    __shared__ int wtot[2];
    const int bb = blockIdx.x;
    const int tid = threadIdx.x;

    // --- sort phase ---
    if (tid < BKT) cnt[tid] = 0;
    __syncthreads();
    const int nD = bcntD[bb];
    const uint* pb = pairsD + (size_t)bb * CAP;
    for (int i = tid; i < nD; i += 1024) atomicAdd(&cnt[(pb[i] >> 16) & 127u], 1);
    __syncthreads();

    if (tid < BKT) {
        const int lane = tid & 63;
        const int wave = tid >> 6;
        const int v = cnt[tid];
        int incl = v;
        #pragma unroll
        for (int d = 1; d < 64; d <<= 1) {
            int u = __shfl_up(incl, d, 64);
            if (lane >= d) incl += u;
        }
        if (lane == 63) wtot[wave] = incl;
        loff[tid] = incl - v;
    }
    __syncthreads();
    if (tid < BKT) {
        const int wave = tid >> 6;
        const int ex = ((wave == 1) ? wtot[0] : 0) + loff[tid];
        loff[tid] = ex;
        degL[tid] = cnt[tid];
        cnt[tid] = 0;                    // reuse as per-local cursor
    }
    __syncthreads();

    for (int i = tid; i < nD; i += 1024) {
        const uint p = pb[i];
        const int local = (int)((p >> 16) & 127u);
        const int pos = atomicAdd(&cnt[local], 1);
        sorted[loff[local] + pos] = (ushort)(p & 0xFFFFu);
    }
    __syncthreads();

    // --- gather phase: 16 waves x 8 nodes, quarter-wave per edge ---
    const int lane = tid & 63;
    const int waveId = tid >> 6;         // 0..15
    const int q = lane & 15;             // col group
    const int g = lane >> 4;             // edge slot 0..3

    #pragma unroll
    for (int i = 0; i < BKT / 16; ++i) {
        const int local = i * 16 + waveId;
        const int node = bb * BKT + local;
        if (node >= N_NODES) continue;
        const int beg = loff[local];
        const int deg = degL[local];

        float a0 = 0.f, a1 = 0.f, a2 = 0.f, a3 = 0.f;
        const int nfull = deg >> 2;
        int e = beg + g;
        for (int it = 0; it < nfull; ++it) {
            const int s = (int)sorted[e];
            e += 4;
            const float ns = rsqrtf(fmaxf((float)outdeg[s], 1.0f));
            const uint2 v = *(const uint2*)(h + (size_t)s * OUT_F + q * 4);
            a0 = fmaf(ns, bf_lo(v.x), a0); a1 = fmaf(ns, bf_hi(v.x), a1);
            a2 = fmaf(ns, bf_lo(v.y), a2); a3 = fmaf(ns, bf_hi(v.y), a3);
        }
        const int rem = deg & 3;
        if (g < rem) {
            const int s = (int)sorted[beg + (deg & ~3) + g];
            const float ns = rsqrtf(fmaxf((float)outdeg[s], 1.0f));
            const uint2 v = *(const uint2*)(h + (size_t)s * OUT_F + q * 4);
            a0 = fmaf(ns, bf_lo(v.x), a0); a1 = fmaf(ns, bf_hi(v.x), a1);
            a2 = fmaf(ns, bf_lo(v.y), a2); a3 = fmaf(ns, bf_hi(v.y), a3);
        }
        a0 += __shfl_xor(a0, 16, 64); a1 += __shfl_xor(a1, 16, 64);
        a2 += __shfl_xor(a2, 16, 64); a3 += __shfl_xor(a3, 16, 64);
        a0 += __shfl_xor(a0, 32, 64); a1 += __shfl_xor(a1, 32, 64);
        a2 += __shfl_xor(a2, 32, 64); a3 += __shfl_xor(a3, 32, 64);

        if (g == 0) {
            const float norm = rsqrtf(fmaxf((float)deg, 1.0f));
            const float4 bb4 = *(const float4*)(b + q * 4);
            float4 o;
            o.x = 1.0f / (1.0f + expf(-(a0 * norm + bb4.x)));
            o.y = 1.0f / (1.0f + expf(-(a1 * norm + bb4.y)));
            o.z = 1.0f / (1.0f + expf(-(a2 * norm + bb4.z)));
            o.w = 1.0f / (1.0f + expf(-(a3 * norm + bb4.w)));
            *(float4*)(out + (size_t)node * OUT_F + q * 4) = o;
        }
    }
}

// ---------------------------------------------------------------------------
extern "C" void kernel_launch(void* const* d_in, const int* in_sizes, int n_in,
                              void* d_out, int out_size, void* d_ws, size_t ws_size,
                              hipStream_t stream) {
    const float* feat = (const float*)d_in[0];
    const int* src    = (const int*)d_in[1];
    const int* dst    = (const int*)d_in[2];
    const float* W    = (const float*)d_in[3];
    const float* b    = (const float*)d_in[4];
    float* out = (float*)d_out;

    char* ws = (char*)d_ws;
    size_t off = 0;
    ushort* h = (ushort*)(ws + off);        off += (size_t)N_NODES * OUT_F * 2;  // 6.4 MB
    int* outdeg = (int*)(ws + off);         off += (size_t)N_NODES * 4;          // 200 KB
    int* bcntD = (int*)(ws + off);          off += (size_t)NB * 4 + 16;
    ushort* Wpk = (ushort*)(ws + off);      off += (size_t)IN_F * OUT_F * 2;     // 32 KB
    uint* pairsD = (uint*)(ws + off);       off += (size_t)NB * CAP * 4;         // 4.8 MB

    prep_kernel<<<9 + (N_NODES / 4 + 255) / 256, 256, 0, stream>>>(
        bcntD, W, Wpk, (int4*)outdeg);

    fused_kernel<<<PARTA_BLOCKS + HIST_BLOCKS + GEMM_BLOCKS, 512, 0, stream>>>(
        src, dst, bcntD, pairsD, outdeg, feat, Wpk, h);

    buckgather_kernel<<<NB, 1024, 0, stream>>>(outdeg, pairsD, bcntD, h, b, out);
}